// Round 2
// baseline (212.927 us; speedup 1.0000x reference)
//
#include <hip/hip_runtime.h>

#define N 8192
#define M 4
#define L 256
#define THREADS 256
#define ROWS 8
#define GRID (N / ROWS)              // 1024 blocks, uniform work
#define PREPBLK 48                   // 48*256 = 12288 threads >= 10240 E + 2048 tc

// ws layout (floats)
#define WS_E 0                       // [5][N]  exp(hazards), stream-major
#define WS_TC (5 * N)                // [N]     compact times
#define WS_PART (6 * N)              // [8][GRID] partials:
                                     //   0..4 cox streams, 5 kj, 6 km, 7 event-sum

__device__ __forceinline__ float waveSum(float v) {
#pragma unroll
    for (int off = 32; off > 0; off >>= 1) v += __shfl_down(v, off, 64);
    return v;
}

__device__ __forceinline__ float4 exp4(float4 h) {
    return make_float4(__expf(h.x), __expf(h.y), __expf(h.z), __expf(h.w));
}

__device__ __forceinline__ float kl4(float4 l, float4 s) {
    float k;
    k  = 0.5f * (s.x * s.x + l.x * l.x) - __logf(s.x) - 0.5f;
    k += 0.5f * (s.y * s.y + l.y * l.y) - __logf(s.y) - 0.5f;
    k += 0.5f * (s.z * s.z + l.z * l.z) - __logf(s.z) - 0.5f;
    k += 0.5f * (s.w * s.w + l.w * l.w) - __logf(s.w) - 0.5f;
    return k;
}

// ---------------- prep: exp table + compact times ----------------
__global__ __launch_bounds__(THREADS) void prep_kernel(
    const float* __restrict__ jlh, const float* __restrict__ mlh,
    const float* __restrict__ target, float* __restrict__ ws)
{
    const int idx = blockIdx.x * THREADS + threadIdx.x;  // [0, 12288)
    float4* E4 = (float4*)(ws + WS_E);
    const float4* jl4 = (const float4*)jlh;
    const float4* ml4 = (const float4*)mlh;

    if (idx < 10240) {
        // E[s][q]: s = idx>>11, q = idx&2047 (2048 f4 per stream)
        const int s = idx >> 11, q = idx & 2047;
        const float4 h = (s == 0) ? jl4[q] : ml4[(s - 1) * 2048 + q];
        E4[idx] = exp4(h);
    } else {
        // compact times: tc[i] = target[2i]
        const int q = idx - 10240;   // [0, 2048)
        const float4* tg4 = (const float4*)target;
        const float4 f1 = tg4[2 * q];
        const float4 f2 = tg4[2 * q + 1];
        ((float4*)(ws + WS_TC))[q] = make_float4(f1.x, f1.z, f2.x, f2.z);
    }
}

// ---------------- main: 8 cox rows + 1/1024 of KL per block ----------------
__global__ __launch_bounds__(THREADS, 4) void main_kernel(
    const float* __restrict__ jlh, const float* __restrict__ mlh,
    const float4* __restrict__ jloc4, const float4* __restrict__ jscale4,
    const float4* __restrict__ mloc4, const float4* __restrict__ mscale4,
    const float* __restrict__ target, float* __restrict__ ws)
{
    const int tid = threadIdx.x;
    const int b = blockIdx.x;
    const int i0 = b * ROWS;

    const float* __restrict__ tc = ws + WS_TC;
    const float4* __restrict__ tc4 = (const float4*)tc;
    const float4* __restrict__ E4 = (const float4*)(ws + WS_E);

    float t_i[ROWS];
#pragma unroll
    for (int r = 0; r < ROWS; ++r) t_i[r] = tc[i0 + r];

    float acc[ROWS][5];
#pragma unroll
    for (int r = 0; r < ROWS; ++r)
#pragma unroll
        for (int s = 0; s < 5; ++s) acc[r][s] = 0.f;

    float kj = 0.f, km = 0.f;
    const int jq = b * 512 + tid;    // joint KL f4 base (2 per thread)
    const int mq = b * 2048 + tid;   // modality KL f4 base (8 per thread)

    // issue first KL loads early — latency hides under cox groups
    float4 A0 = jloc4[jq],       S0 = jscale4[jq];
    float4 A1 = jloc4[jq + 256], S1 = jscale4[jq + 256];

    // staggered group order: blocks start their j-sweep at different offsets,
    // breaking the all-CUs-hit-the-same-L2-line lockstep.
#define COX(g) { \
    const int q = (((g) + (b & 7)) & 7) * THREADS + tid; \
    const float4 t4 = tc4[q]; \
    const float4 e0 = E4[q]; \
    const float4 e1 = E4[2048 + q]; \
    const float4 e2 = E4[4096 + q]; \
    const float4 e3 = E4[6144 + q]; \
    const float4 e4 = E4[8192 + q]; \
    _Pragma("unroll") \
    for (int r = 0; r < ROWS; ++r) { \
        const float ti = t_i[r]; \
        const float m0 = (t4.x >= ti) ? 1.f : 0.f; \
        const float m1 = (t4.y >= ti) ? 1.f : 0.f; \
        const float m2 = (t4.z >= ti) ? 1.f : 0.f; \
        const float m3 = (t4.w >= ti) ? 1.f : 0.f; \
        acc[r][0] = fmaf(m0, e0.x, fmaf(m1, e0.y, fmaf(m2, e0.z, fmaf(m3, e0.w, acc[r][0])))); \
        acc[r][1] = fmaf(m0, e1.x, fmaf(m1, e1.y, fmaf(m2, e1.z, fmaf(m3, e1.w, acc[r][1])))); \
        acc[r][2] = fmaf(m0, e2.x, fmaf(m1, e2.y, fmaf(m2, e2.z, fmaf(m3, e2.w, acc[r][2])))); \
        acc[r][3] = fmaf(m0, e3.x, fmaf(m1, e3.y, fmaf(m2, e3.z, fmaf(m3, e3.w, acc[r][3])))); \
        acc[r][4] = fmaf(m0, e4.x, fmaf(m1, e4.y, fmaf(m2, e4.z, fmaf(m3, e4.w, acc[r][4])))); \
    } }

    COX(0);
    kj += kl4(A0, S0); A0 = mloc4[mq];        S0 = mscale4[mq];
    COX(1);
    kj += kl4(A1, S1); A1 = mloc4[mq + 256];  S1 = mscale4[mq + 256];
    COX(2);
    km += kl4(A0, S0); A0 = mloc4[mq + 512];  S0 = mscale4[mq + 512];
    COX(3);
    km += kl4(A1, S1); A1 = mloc4[mq + 768];  S1 = mscale4[mq + 768];
    COX(4);
    km += kl4(A0, S0); A0 = mloc4[mq + 1024]; S0 = mscale4[mq + 1024];
    COX(5);
    km += kl4(A1, S1); A1 = mloc4[mq + 1280]; S1 = mscale4[mq + 1280];
    COX(6);
    km += kl4(A0, S0); A0 = mloc4[mq + 1536]; S0 = mscale4[mq + 1536];
    COX(7);
    km += kl4(A1, S1); A1 = mloc4[mq + 1792]; S1 = mscale4[mq + 1792];
    km += kl4(A0, S0);
    km += kl4(A1, S1);
#undef COX

    // ---- reductions ----
#pragma unroll
    for (int r = 0; r < ROWS; ++r)
#pragma unroll
        for (int s = 0; s < 5; ++s) acc[r][s] = waveSum(acc[r][s]);
    kj = waveSum(kj);
    km = waveSum(km);

    __shared__ float red[4][42];
    const int lane = tid & 63, wid = tid >> 6;
    if (lane == 0) {
#pragma unroll
        for (int r = 0; r < ROWS; ++r)
#pragma unroll
            for (int s = 0; s < 5; ++s) red[wid][r * 5 + s] = acc[r][s];
        red[wid][40] = kj;
        red[wid][41] = km;
    }
    __syncthreads();

    __shared__ float cr[40];
    if (tid < 40) {
        const int r = tid / 5, s = tid % 5;
        const float risk = red[0][tid] + red[1][tid] + red[2][tid] + red[3][tid];
        const float ev = target[2 * (i0 + r) + 1];
        const float h = (s == 0) ? jlh[i0 + r] : mlh[(s - 1) * N + i0 + r];
        cr[tid] = ev * (h - __logf(risk));
    } else if (tid == 40) {
        ws[WS_PART + 5 * GRID + b] = red[0][40] + red[1][40] + red[2][40] + red[3][40];
    } else if (tid == 41) {
        ws[WS_PART + 6 * GRID + b] = red[0][41] + red[1][41] + red[2][41] + red[3][41];
    } else if (tid == 42) {
        float e = 0.f;
#pragma unroll
        for (int r = 0; r < ROWS; ++r) e += target[2 * (i0 + r) + 1];
        ws[WS_PART + 7 * GRID + b] = e;
    }
    __syncthreads();

    if (tid < 5) {  // per-stream sum over the 8 rows
        float v = 0.f;
#pragma unroll
        for (int r = 0; r < ROWS; ++r) v += cr[tid + 5 * r];
        ws[WS_PART + tid * GRID + b] = v;
    }
}

// ---------------- finalize: tiny, coalesced ----------------
__global__ __launch_bounds__(THREADS) void finalize_kernel(
    const float* __restrict__ ws, const float* __restrict__ alpha_p,
    const float* __restrict__ beta_p, float* __restrict__ out)
{
    const int tid = threadIdx.x;
    float v[8];
#pragma unroll
    for (int k = 0; k < 8; ++k) {
        float x = 0.f;
#pragma unroll
        for (int it = 0; it < GRID / THREADS; ++it)
            x += ws[WS_PART + k * GRID + it * THREADS + tid];
        v[k] = waveSum(x);
    }
    __shared__ float red[8][4];
    const int lane = tid & 63, wid = tid >> 6;
    if (lane == 0)
#pragma unroll
        for (int k = 0; k < 8; ++k) red[k][wid] = v[k];
    __syncthreads();
    if (tid == 0) {
        float t[8];
#pragma unroll
        for (int k = 0; k < 8; ++k) t[k] = red[k][0] + red[k][1] + red[k][2] + red[k][3];
        const float EV = t[7];
        const float alpha = alpha_p[0], beta = beta_p[0];
        const float cox_j = -t[0] / EV;
        const float cox_m = -(t[1] + t[2] + t[3] + t[4]) / EV;
        out[0] = cox_j + beta * (t[5] / (float)N) + alpha * (cox_m + beta * (t[6] / (float)N));
    }
}

extern "C" void kernel_launch(void* const* d_in, const int* in_sizes, int n_in,
                              void* d_out, int out_size, void* d_ws, size_t ws_size,
                              hipStream_t stream) {
    const float* jlh    = (const float*)d_in[0];  // (N,)
    const float* mlh    = (const float*)d_in[1];  // (M,N)
    const float* jloc   = (const float*)d_in[2];  // (N,L)
    const float* jscale = (const float*)d_in[3];  // (N,L)
    const float* mloc   = (const float*)d_in[4];  // (M,N,L)
    const float* mscale = (const float*)d_in[5];  // (M,N,L)
    const float* target = (const float*)d_in[6];  // (N,2)
    const float* alpha  = (const float*)d_in[7];
    const float* beta   = (const float*)d_in[8];
    float* out = (float*)d_out;
    float* ws  = (float*)d_ws;

    prep_kernel<<<PREPBLK, THREADS, 0, stream>>>(jlh, mlh, target, ws);
    main_kernel<<<GRID, THREADS, 0, stream>>>(
        jlh, mlh, (const float4*)jloc, (const float4*)jscale,
        (const float4*)mloc, (const float4*)mscale, target, ws);
    finalize_kernel<<<1, THREADS, 0, stream>>>(ws, alpha, beta, out);
}

// Round 3
// 144.116 us; speedup vs baseline: 1.4775x; 1.4775x over previous
//
#include <hip/hip_runtime.h>

#define N 8192
#define M 4
#define L 256
#define THREADS 256
#define R_B 16                        // rows per cox block
#define R_W 4                         // rows per wave (4 waves)
#define COXBLK (N / R_B)              // 512 cox blocks
#define KLBLK 512                     // 512 KL blocks
#define GRID (COXBLK + KLBLK)         // 1024, interleaved even=cox / odd=KL
#define NTILES 8                      // 8192 / 1024 j's per tile
#define PREPBLK 48                    // 48*256 = 12288 >= 10240 E + 2048 tc

// ws layout (floats)
#define WS_E 0                        // [5][N]  exp(hazards), stream-major
#define WS_TC (5 * N)                 // [N]     compact times
#define WS_PART (6 * N)               // [8][512]: 0..4 cox streams, 5 kj, 6 km, 7 ev

__device__ __forceinline__ float waveSum(float v) {
#pragma unroll
    for (int off = 32; off > 0; off >>= 1) v += __shfl_down(v, off, 64);
    return v;
}

__device__ __forceinline__ float4 exp4(float4 h) {
    return make_float4(__expf(h.x), __expf(h.y), __expf(h.z), __expf(h.w));
}

__device__ __forceinline__ float kl4(float4 l, float4 s) {
    float k;
    k  = 0.5f * (s.x * s.x + l.x * l.x) - __logf(s.x) - 0.5f;
    k += 0.5f * (s.y * s.y + l.y * l.y) - __logf(s.y) - 0.5f;
    k += 0.5f * (s.z * s.z + l.z * l.z) - __logf(s.z) - 0.5f;
    k += 0.5f * (s.w * s.w + l.w * l.w) - __logf(s.w) - 0.5f;
    return k;
}

// ---------------- prep: exp table + compact times ----------------
__global__ __launch_bounds__(THREADS) void prep_kernel(
    const float* __restrict__ jlh, const float* __restrict__ mlh,
    const float* __restrict__ target, float* __restrict__ ws)
{
    const int idx = blockIdx.x * THREADS + threadIdx.x;  // [0, 12288)
    float4* E4 = (float4*)(ws + WS_E);
    const float4* jl4 = (const float4*)jlh;
    const float4* ml4 = (const float4*)mlh;

    if (idx < 10240) {
        const int s = idx >> 11, q = idx & 2047;         // 2048 f4 per stream
        const float4 h = (s == 0) ? jl4[q] : ml4[(s - 1) * 2048 + q];
        E4[idx] = exp4(h);
    } else {
        const int q = idx - 10240;                       // [0, 2048)
        const float4* tg4 = (const float4*)target;
        const float4 f1 = tg4[2 * q];
        const float4 f2 = tg4[2 * q + 1];
        ((float4*)(ws + WS_TC))[q] = make_float4(f1.x, f1.z, f2.x, f2.z);
    }
}

// ---------------- main: even blocks = cox(16 rows, LDS-staged), odd = KL ----
__global__ __launch_bounds__(THREADS) void main_kernel(
    const float* __restrict__ jlh, const float* __restrict__ mlh,
    const float4* __restrict__ jloc4, const float4* __restrict__ jscale4,
    const float4* __restrict__ mloc4, const float4* __restrict__ mscale4,
    const float* __restrict__ target, float* __restrict__ ws)
{
    __shared__ float lds_tc[2][1024];
    __shared__ float lds_E[2][5][1024];
    __shared__ float red[4][20];
    __shared__ float cr[80];

    const int tid = threadIdx.x;
    const int bid = blockIdx.x;
    const int lane = tid & 63, w = tid >> 6;

    if ((bid & 1) == 0) {
        // ================= Cox path =================
        const int cb = bid >> 1;          // 0..511
        const int i0 = cb * R_B;

        const float* __restrict__ tc = ws + WS_TC;
        const float4* __restrict__ tc4g = (const float4*)tc;
        const float4* __restrict__ E4 = (const float4*)(ws + WS_E);

        float t_i[R_W];
#pragma unroll
        for (int r = 0; r < R_W; ++r) t_i[r] = tc[i0 + R_W * w + r];

        float acc[R_W][5];
#pragma unroll
        for (int r = 0; r < R_W; ++r)
#pragma unroll
            for (int s = 0; s < 5; ++s) acc[r][s] = 0.f;

        // staging registers (tile t+1 in flight during compute of tile t)
        float4 stc, se0, se1, se2, se3, se4;

#define SLOAD(t) { \
        const int q = (t) * 256 + tid; \
        stc = tc4g[q]; \
        se0 = E4[q];          se1 = E4[2048 + q];  se2 = E4[4096 + q]; \
        se3 = E4[6144 + q];   se4 = E4[8192 + q]; }

#define SWRITE(t) { \
        const int bb = (t) & 1; \
        ((float4*)lds_tc[bb])[tid]    = stc; \
        ((float4*)lds_E[bb][0])[tid]  = se0; \
        ((float4*)lds_E[bb][1])[tid]  = se1; \
        ((float4*)lds_E[bb][2])[tid]  = se2; \
        ((float4*)lds_E[bb][3])[tid]  = se3; \
        ((float4*)lds_E[bb][4])[tid]  = se4; }

        SLOAD(0); SWRITE(0);

        for (int t = 0; t < NTILES; ++t) {
            __syncthreads();
            if (t < NTILES - 1) SLOAD(t + 1);      // issue early, hide under compute

            const int bb = t & 1;
            const float4* __restrict__ ltc = (const float4*)lds_tc[bb];
            const float4* __restrict__ le0 = (const float4*)lds_E[bb][0];
            const float4* __restrict__ le1 = (const float4*)lds_E[bb][1];
            const float4* __restrict__ le2 = (const float4*)lds_E[bb][2];
            const float4* __restrict__ le3 = (const float4*)lds_E[bb][3];
            const float4* __restrict__ le4 = (const float4*)lds_E[bb][4];

#pragma unroll
            for (int g = 0; g < 4; ++g) {          // wave covers 4*64*4 = 1024 j's
                const int q = g * 64 + lane;
                const float4 t4 = ltc[q];
                const float4 e0 = le0[q];
                const float4 e1 = le1[q];
                const float4 e2 = le2[q];
                const float4 e3 = le3[q];
                const float4 e4 = le4[q];
#pragma unroll
                for (int r = 0; r < R_W; ++r) {
                    const float ti = t_i[r];
                    const float m0 = (t4.x >= ti) ? 1.f : 0.f;
                    const float m1 = (t4.y >= ti) ? 1.f : 0.f;
                    const float m2 = (t4.z >= ti) ? 1.f : 0.f;
                    const float m3 = (t4.w >= ti) ? 1.f : 0.f;
                    acc[r][0] = fmaf(m0, e0.x, fmaf(m1, e0.y, fmaf(m2, e0.z, fmaf(m3, e0.w, acc[r][0]))));
                    acc[r][1] = fmaf(m0, e1.x, fmaf(m1, e1.y, fmaf(m2, e1.z, fmaf(m3, e1.w, acc[r][1]))));
                    acc[r][2] = fmaf(m0, e2.x, fmaf(m1, e2.y, fmaf(m2, e2.z, fmaf(m3, e2.w, acc[r][2]))));
                    acc[r][3] = fmaf(m0, e3.x, fmaf(m1, e3.y, fmaf(m2, e3.z, fmaf(m3, e3.w, acc[r][3]))));
                    acc[r][4] = fmaf(m0, e4.x, fmaf(m1, e4.y, fmaf(m2, e4.z, fmaf(m3, e4.w, acc[r][4]))));
                }
            }
            if (t < NTILES - 1) SWRITE(t + 1);     // regs -> LDS after compute
        }
#undef SLOAD
#undef SWRITE

        // ---- reductions: wave-local, then per-row epilogue ----
#pragma unroll
        for (int r = 0; r < R_W; ++r)
#pragma unroll
            for (int s = 0; s < 5; ++s) acc[r][s] = waveSum(acc[r][s]);
        if (lane == 0) {
#pragma unroll
            for (int r = 0; r < R_W; ++r)
#pragma unroll
                for (int s = 0; s < 5; ++s) red[w][r * 5 + s] = acc[r][s];
        }
        __syncthreads();

        if (tid < 80) {                    // (row 0..15) x (stream 0..4)
            const int rr = tid / 5, s = tid % 5;
            const float risk = red[rr >> 2][(rr & 3) * 5 + s];
            const float ev = target[2 * (i0 + rr) + 1];
            const float h = (s == 0) ? jlh[i0 + rr] : mlh[(s - 1) * N + i0 + rr];
            cr[tid] = ev * (h - __logf(risk));
        }
        __syncthreads();

        if (tid < 5) {
            float v = 0.f;
#pragma unroll
            for (int rr = 0; rr < R_B; ++rr) v += cr[rr * 5 + tid];
            ws[WS_PART + tid * COXBLK + cb] = v;
        } else if (tid == 5) {
            float e = 0.f;
#pragma unroll
            for (int rr = 0; rr < R_B; ++rr) e += target[2 * (i0 + rr) + 1];
            ws[WS_PART + 7 * COXBLK + cb] = e;
        }
    } else {
        // ================= KL path (pure streaming) =================
        const int kb = bid >> 1;          // 0..511
        float kj = 0.f, km = 0.f;
#pragma unroll
        for (int it = 0; it < 4; ++it) {              // joint: 1024 f4/block
            const int idx = kb * 1024 + it * 256 + tid;
            kj += kl4(jloc4[idx], jscale4[idx]);
        }
#pragma unroll
        for (int it = 0; it < 16; ++it) {             // modality: 4096 f4/block
            const int idx = kb * 4096 + it * 256 + tid;
            km += kl4(mloc4[idx], mscale4[idx]);
        }
        kj = waveSum(kj);
        km = waveSum(km);
        if (lane == 0) { red[w][0] = kj; red[w][1] = km; }
        __syncthreads();
        if (tid == 0)
            ws[WS_PART + 5 * KLBLK + kb] = red[0][0] + red[1][0] + red[2][0] + red[3][0];
        if (tid == 1)
            ws[WS_PART + 6 * KLBLK + kb] = red[0][1] + red[1][1] + red[2][1] + red[3][1];
    }
}

// ---------------- finalize: tiny, coalesced ----------------
__global__ __launch_bounds__(THREADS) void finalize_kernel(
    const float* __restrict__ ws, const float* __restrict__ alpha_p,
    const float* __restrict__ beta_p, float* __restrict__ out)
{
    const int tid = threadIdx.x;
    float v[8];
#pragma unroll
    for (int k = 0; k < 8; ++k) {
        float x = 0.f;
#pragma unroll
        for (int it = 0; it < 512 / THREADS; ++it)
            x += ws[WS_PART + k * 512 + it * THREADS + tid];
        v[k] = waveSum(x);
    }
    __shared__ float red[8][4];
    const int lane = tid & 63, wid = tid >> 6;
    if (lane == 0)
#pragma unroll
        for (int k = 0; k < 8; ++k) red[k][wid] = v[k];
    __syncthreads();
    if (tid == 0) {
        float t[8];
#pragma unroll
        for (int k = 0; k < 8; ++k) t[k] = red[k][0] + red[k][1] + red[k][2] + red[k][3];
        const float EV = t[7];
        const float alpha = alpha_p[0], beta = beta_p[0];
        const float cox_j = -t[0] / EV;
        const float cox_m = -(t[1] + t[2] + t[3] + t[4]) / EV;
        out[0] = cox_j + beta * (t[5] / (float)N) + alpha * (cox_m + beta * (t[6] / (float)N));
    }
}

extern "C" void kernel_launch(void* const* d_in, const int* in_sizes, int n_in,
                              void* d_out, int out_size, void* d_ws, size_t ws_size,
                              hipStream_t stream) {
    const float* jlh    = (const float*)d_in[0];  // (N,)
    const float* mlh    = (const float*)d_in[1];  // (M,N)
    const float* jloc   = (const float*)d_in[2];  // (N,L)
    const float* jscale = (const float*)d_in[3];  // (N,L)
    const float* mloc   = (const float*)d_in[4];  // (M,N,L)
    const float* mscale = (const float*)d_in[5];  // (M,N,L)
    const float* target = (const float*)d_in[6];  // (N,2)
    const float* alpha  = (const float*)d_in[7];
    const float* beta   = (const float*)d_in[8];
    float* out = (float*)d_out;
    float* ws  = (float*)d_ws;

    prep_kernel<<<PREPBLK, THREADS, 0, stream>>>(jlh, mlh, target, ws);
    main_kernel<<<GRID, THREADS, 0, stream>>>(
        jlh, mlh, (const float4*)jloc, (const float4*)jscale,
        (const float4*)mloc, (const float4*)mscale, target, ws);
    finalize_kernel<<<1, THREADS, 0, stream>>>(ws, alpha, beta, out);
}

// Round 4
// 136.879 us; speedup vs baseline: 1.5556x; 1.0529x over previous
//
#include <hip/hip_runtime.h>

#define N 8192
#define M 4
#define L 256
#define THREADS 256
#define R_B 8                         // rows per cox block
#define COXBLK (N / R_B)              // 1024 cox blocks
#define KLBLK 1024                    // 1024 KL blocks
#define GRID (COXBLK + KLBLK)         // 2048, interleaved even=cox / odd=KL
#define PREPBLK 48                    // 48*256 = 12288 >= 10240 E + 2048 tc

// ws layout (floats)
#define WS_E 0                        // [5][N]  exp(hazards), stream-major
#define WS_TC (5 * N)                 // [N]     compact times
#define WS_PART (6 * N)               // [8][1024]: 0..4 cox streams, 5 kj, 6 km, 7 ev

__device__ __forceinline__ float waveSum(float v) {
#pragma unroll
    for (int off = 32; off > 0; off >>= 1) v += __shfl_down(v, off, 64);
    return v;
}

__device__ __forceinline__ float4 exp4(float4 h) {
    return make_float4(__expf(h.x), __expf(h.y), __expf(h.z), __expf(h.w));
}

__device__ __forceinline__ float kl4(float4 l, float4 s) {
    float k;
    k  = 0.5f * (s.x * s.x + l.x * l.x) - __logf(s.x) - 0.5f;
    k += 0.5f * (s.y * s.y + l.y * l.y) - __logf(s.y) - 0.5f;
    k += 0.5f * (s.z * s.z + l.z * l.z) - __logf(s.z) - 0.5f;
    k += 0.5f * (s.w * s.w + l.w * l.w) - __logf(s.w) - 0.5f;
    return k;
}

// ---------------- prep: exp table + compact times ----------------
__global__ __launch_bounds__(THREADS) void prep_kernel(
    const float* __restrict__ jlh, const float* __restrict__ mlh,
    const float* __restrict__ target, float* __restrict__ ws)
{
    const int idx = blockIdx.x * THREADS + threadIdx.x;  // [0, 12288)
    float4* E4 = (float4*)(ws + WS_E);
    const float4* jl4 = (const float4*)jlh;
    const float4* ml4 = (const float4*)mlh;

    if (idx < 10240) {
        const int s = idx >> 11, q = idx & 2047;         // 2048 f4 per stream
        const float4 h = (s == 0) ? jl4[q] : ml4[(s - 1) * 2048 + q];
        E4[idx] = exp4(h);
    } else {
        const int q = idx - 10240;                       // [0, 2048)
        const float4* tg4 = (const float4*)target;
        const float4 f1 = tg4[2 * q];
        const float4 f2 = tg4[2 * q + 1];
        ((float4*)(ws + WS_TC))[q] = make_float4(f1.x, f1.z, f2.x, f2.z);
    }
}

// ------- main: even blocks = cox (8 rows, j-split across waves), odd = KL ----
__global__ __launch_bounds__(THREADS) void main_kernel(
    const float* __restrict__ jlh, const float* __restrict__ mlh,
    const float4* __restrict__ jloc4, const float4* __restrict__ jscale4,
    const float4* __restrict__ mloc4, const float4* __restrict__ mscale4,
    const float* __restrict__ target, float* __restrict__ ws)
{
    __shared__ float red[4][R_B * 5];   // 640 B — negligible, LDS no longer caps occupancy
    __shared__ float cr[R_B * 5];

    const int tid = threadIdx.x;
    const int bid = blockIdx.x;
    const int lane = tid & 63, w = tid >> 6;

    if ((bid & 1) == 0) {
        // ================= Cox path =================
        const int cb = bid >> 1;          // 0..1023
        const int i0 = cb * R_B;

        const float* __restrict__ tc = ws + WS_TC;
        const float4* __restrict__ tc4 = (const float4*)tc;
        const float4* __restrict__ E4 = (const float4*)(ws + WS_E);

        float t_i[R_B];
#pragma unroll
        for (int r = 0; r < R_B; ++r) t_i[r] = tc[i0 + r];

        float acc[R_B][5];
#pragma unroll
        for (int r = 0; r < R_B; ++r)
#pragma unroll
            for (int s = 0; s < 5; ++s) acc[r][s] = 0.f;

        // this wave's j-chunk (2048 j's = 512 f4), staggered per block
        const int chunk = (w + cb) & 3;
        const int base = chunk * 512;
        const int g0 = cb & 7;

#pragma unroll 4
        for (int gi = 0; gi < 8; ++gi) {
            const int q = base + ((g0 + gi) & 7) * 64 + lane;
            const float4 t4 = tc4[q];
            const float4 e0 = E4[q];
            const float4 e1 = E4[2048 + q];
            const float4 e2 = E4[4096 + q];
            const float4 e3 = E4[6144 + q];
            const float4 e4 = E4[8192 + q];
#pragma unroll
            for (int r = 0; r < R_B; ++r) {
                const float ti = t_i[r];
                const float m0 = (t4.x >= ti) ? 1.f : 0.f;
                const float m1 = (t4.y >= ti) ? 1.f : 0.f;
                const float m2 = (t4.z >= ti) ? 1.f : 0.f;
                const float m3 = (t4.w >= ti) ? 1.f : 0.f;
                acc[r][0] = fmaf(m0, e0.x, fmaf(m1, e0.y, fmaf(m2, e0.z, fmaf(m3, e0.w, acc[r][0]))));
                acc[r][1] = fmaf(m0, e1.x, fmaf(m1, e1.y, fmaf(m2, e1.z, fmaf(m3, e1.w, acc[r][1]))));
                acc[r][2] = fmaf(m0, e2.x, fmaf(m1, e2.y, fmaf(m2, e2.z, fmaf(m3, e2.w, acc[r][2]))));
                acc[r][3] = fmaf(m0, e3.x, fmaf(m1, e3.y, fmaf(m2, e3.z, fmaf(m3, e3.w, acc[r][3]))));
                acc[r][4] = fmaf(m0, e4.x, fmaf(m1, e4.y, fmaf(m2, e4.z, fmaf(m3, e4.w, acc[r][4]))));
            }
        }

        // ---- cross-wave reduction: each wave holds partial risks for all rows ----
#pragma unroll
        for (int r = 0; r < R_B; ++r)
#pragma unroll
            for (int s = 0; s < 5; ++s) acc[r][s] = waveSum(acc[r][s]);
        if (lane == 0) {
#pragma unroll
            for (int r = 0; r < R_B; ++r)
#pragma unroll
                for (int s = 0; s < 5; ++s) red[w][r * 5 + s] = acc[r][s];
        }
        __syncthreads();

        if (tid < R_B * 5) {               // (row 0..7) x (stream 0..4)
            const int rr = tid / 5, s = tid % 5;
            const float risk = red[0][tid] + red[1][tid] + red[2][tid] + red[3][tid];
            const float ev = target[2 * (i0 + rr) + 1];
            const float h = (s == 0) ? jlh[i0 + rr] : mlh[(s - 1) * N + i0 + rr];
            cr[tid] = ev * (h - __logf(risk));
        }
        __syncthreads();

        if (tid < 5) {
            float v = 0.f;
#pragma unroll
            for (int rr = 0; rr < R_B; ++rr) v += cr[rr * 5 + tid];
            ws[WS_PART + tid * COXBLK + cb] = v;
        } else if (tid == 5) {
            float e = 0.f;
#pragma unroll
            for (int rr = 0; rr < R_B; ++rr) e += target[2 * (i0 + rr) + 1];
            ws[WS_PART + 7 * COXBLK + cb] = e;
        }
    } else {
        // ================= KL path (pure streaming, no LDS tax) =================
        const int kb = bid >> 1;          // 0..1023
        float kj = 0.f, km = 0.f;
#pragma unroll
        for (int it = 0; it < 2; ++it) {              // joint: 512 f4/block
            const int idx = kb * 512 + it * 256 + tid;
            kj += kl4(jloc4[idx], jscale4[idx]);
        }
#pragma unroll
        for (int it = 0; it < 8; ++it) {              // modality: 2048 f4/block
            const int idx = kb * 2048 + it * 256 + tid;
            km += kl4(mloc4[idx], mscale4[idx]);
        }
        kj = waveSum(kj);
        km = waveSum(km);
        if (lane == 0) { red[w][0] = kj; red[w][1] = km; }
        __syncthreads();
        if (tid == 0)
            ws[WS_PART + 5 * KLBLK + kb] = red[0][0] + red[1][0] + red[2][0] + red[3][0];
        if (tid == 1)
            ws[WS_PART + 6 * KLBLK + kb] = red[0][1] + red[1][1] + red[2][1] + red[3][1];
    }
}

// ---------------- finalize: tiny, coalesced ----------------
__global__ __launch_bounds__(THREADS) void finalize_kernel(
    const float* __restrict__ ws, const float* __restrict__ alpha_p,
    const float* __restrict__ beta_p, float* __restrict__ out)
{
    const int tid = threadIdx.x;
    float v[8];
#pragma unroll
    for (int k = 0; k < 8; ++k) {
        float x = 0.f;
#pragma unroll
        for (int it = 0; it < COXBLK / THREADS; ++it)
            x += ws[WS_PART + k * COXBLK + it * THREADS + tid];
        v[k] = waveSum(x);
    }
    __shared__ float red[8][4];
    const int lane = tid & 63, wid = tid >> 6;
    if (lane == 0)
#pragma unroll
        for (int k = 0; k < 8; ++k) red[k][wid] = v[k];
    __syncthreads();
    if (tid == 0) {
        float t[8];
#pragma unroll
        for (int k = 0; k < 8; ++k) t[k] = red[k][0] + red[k][1] + red[k][2] + red[k][3];
        const float EV = t[7];
        const float alpha = alpha_p[0], beta = beta_p[0];
        const float cox_j = -t[0] / EV;
        const float cox_m = -(t[1] + t[2] + t[3] + t[4]) / EV;
        out[0] = cox_j + beta * (t[5] / (float)N) + alpha * (cox_m + beta * (t[6] / (float)N));
    }
}

extern "C" void kernel_launch(void* const* d_in, const int* in_sizes, int n_in,
                              void* d_out, int out_size, void* d_ws, size_t ws_size,
                              hipStream_t stream) {
    const float* jlh    = (const float*)d_in[0];  // (N,)
    const float* mlh    = (const float*)d_in[1];  // (M,N)
    const float* jloc   = (const float*)d_in[2];  // (N,L)
    const float* jscale = (const float*)d_in[3];  // (N,L)
    const float* mloc   = (const float*)d_in[4];  // (M,N,L)
    const float* mscale = (const float*)d_in[5];  // (M,N,L)
    const float* target = (const float*)d_in[6];  // (N,2)
    const float* alpha  = (const float*)d_in[7];
    const float* beta   = (const float*)d_in[8];
    float* out = (float*)d_out;
    float* ws  = (float*)d_ws;

    prep_kernel<<<PREPBLK, THREADS, 0, stream>>>(jlh, mlh, target, ws);
    main_kernel<<<GRID, THREADS, 0, stream>>>(
        jlh, mlh, (const float4*)jloc, (const float4*)jscale,
        (const float4*)mloc, (const float4*)mscale, target, ws);
    finalize_kernel<<<1, THREADS, 0, stream>>>(ws, alpha, beta, out);
}